// Round 9
// baseline (4122.430 us; speedup 1.0000x reference)
//
#include <hip/hip_runtime.h>
#include <hip/hip_fp16.h>

#define BB 64
#define SS 1024
#define MEL 60
#define HH 180
#define G4 720    // 4*H
#define GP 192    // per-gate padded hidden
#define G4P 768   // 4*GP
#define NKS 6     // k-steps of 32 (K padded to 192)
#define NL 4
#define NPOST 8192
#define NOUT 300
#define NOUTP 320
#define KSPL 16
#define TT 128
#define CH 64
#define NCH (SS / CH)
#define NKP 96    // k-pair slots for wih (192/2)

typedef _Float16 f16x8 __attribute__((ext_vector_type(8)));
typedef float f32x4 __attribute__((ext_vector_type(4)));

#if defined(__has_builtin)
#if __has_builtin(__builtin_amdgcn_fdot2)
#define HAVE_FDOT2 1
#endif
#endif
#ifndef HAVE_FDOT2
#define HAVE_FDOT2 0
#endif

__device__ __forceinline__ float fdot2u(unsigned int w, unsigned int h, float acc) {
#if HAVE_FDOT2
    typedef _Float16 h2_t __attribute__((ext_vector_type(2)));
    union U { unsigned int u; h2_t v; };
    U a, b;
    a.u = w; b.u = h;
    return __builtin_amdgcn_fdot2(a.v, b.v, acc, false);
#else
    __half2 aw = *reinterpret_cast<const __half2*>(&w);
    __half2 ah = *reinterpret_cast<const __half2*>(&h);
    acc += __half2float(__low2half(aw)) * __half2float(__low2half(ah));
    acc += __half2float(__high2half(aw)) * __half2float(__high2half(ah));
    return acc;
#endif
}

union WU { uint4 u; f16x8 f; };

__device__ __forceinline__ float f16get(uint2 v, int r) {
    unsigned u = (r < 2) ? v.x : v.y;
    unsigned short s = (unsigned short)((r & 1) ? (u >> 16) : (u & 0xffffu));
    return __half2float(__ushort_as_half(s));
}

// ---------------- prep ----------------
// Recurrent MFMA B-frags: wmf[l][wv 12][q 4][ks 6][lane 64] = 8 f16:
//   elem j = whh[l][q*180 + hid][k],  hid = 16*wv + (lane&15),  k = 32*ks + 8*(lane>>4) + j
__global__ void prep_wmf(const float* __restrict__ whh, uint4* __restrict__ wmf) {
    int idx = blockIdx.x * blockDim.x + threadIdx.x;
    int total = NL * 12 * 4 * NKS * 64;
    if (idx >= total) return;
    int l = idx / (12 * 4 * NKS * 64);
    int r1 = idx % (12 * 4 * NKS * 64);
    int wv = r1 / (4 * NKS * 64);
    int r2 = r1 % (4 * NKS * 64);
    int q = r2 / (NKS * 64);
    int r3 = r2 % (NKS * 64);
    int ks = r3 / 64, lane = r3 % 64;
    int hid = wv * 16 + (lane & 15);
    unsigned short v[8];
    #pragma unroll
    for (int j = 0; j < 8; ++j) {
        int k = ks * 32 + ((lane >> 4) << 3) + j;
        float f = (hid < HH && k < HH) ? whh[((size_t)l * G4 + q * HH + hid) * HH + k] : 0.f;
        v[j] = __half_as_ushort(__float2half(f));
    }
    uint4 u;
    u.x = (unsigned)v[0] | ((unsigned)v[1] << 16);
    u.y = (unsigned)v[2] | ((unsigned)v[3] << 16);
    u.z = (unsigned)v[4] | ((unsigned)v[5] << 16);
    u.w = (unsigned)v[6] | ((unsigned)v[7] << 16);
    wmf[idx] = u;
}

// wihP: [l][col 768][kp 96] uint = packed f16 pair along k; zero outside valid
__global__ void prep_wihP(const float* __restrict__ wih0, const float* __restrict__ wih_rest,
                          unsigned int* __restrict__ w) {
    int idx = blockIdx.x * blockDim.x + threadIdx.x;
    int total = NL * G4P * NKP;
    if (idx >= total) return;
    int l = idx / (G4P * NKP);
    int r = idx % (G4P * NKP);
    int col = r / NKP, kp = r % NKP;
    int q = col / GP, hid = col % GP;
    int K = (l == 0) ? MEL : HH;
    float a = 0.f, b = 0.f;
    if (hid < HH && 2 * kp < K) {
        int g = q * HH + hid;
        const float* src = (l == 0) ? (wih0 + (size_t)g * MEL)
                                    : (wih_rest + ((size_t)(l - 1) * G4 + g) * HH);
        a = src[2 * kp]; b = src[2 * kp + 1];
    }
    __half2 h2 = __floats2half2_rn(a, b);
    w[idx] = *(unsigned int*)&h2;
}

// bsP: [l][col 768] fp32, zero in pad
__global__ void prep_bsumP(const float* __restrict__ bih, const float* __restrict__ bhh,
                           float* __restrict__ bsP) {
    int idx = blockIdx.x * blockDim.x + threadIdx.x;
    if (idx >= NL * G4P) return;
    int l = idx / G4P, col = idx % G4P;
    int q = col / GP, hid = col % GP;
    float v = 0.f;
    if (hid < HH) {
        int g = l * G4 + q * HH + hid;
        v = bih[g] + bhh[g];
    }
    bsP[idx] = v;
}

// ---------------- mel smooth residual block ----------------
template <typename TIN>
__global__ __launch_bounds__(256) void mel_block(const TIN* __restrict__ in,
                                                 __half* __restrict__ out,
                                                 const float* __restrict__ w,
                                                 const float* __restrict__ bias) {
    __shared__ float xt[TT + 4][MEL];
    __shared__ float ws[900];
    __shared__ float bs[MEL];
    int bb = blockIdx.x;
    int t0 = blockIdx.y * TT;
    int tid = threadIdx.x;
    const TIN* inb = in + (size_t)bb * SS * MEL;
    for (int idx = tid; idx < (TT + 4) * MEL; idx += 256) {
        int tt = idx / MEL, ch = idx % MEL;
        int t = t0 + tt - 2;
        xt[tt][ch] = (t >= 0 && t < SS) ? (float)inb[(size_t)t * MEL + ch] : 0.f;
    }
    for (int idx = tid; idx < 900; idx += 256) ws[idx] = w[idx];
    if (tid < MEL) bs[tid] = bias[(tid % 3) * 20 + tid / 3];
    __syncthreads();
    for (int idx = tid; idx < TT * MEL; idx += 256) {
        int tt = idx / MEL, ch = idx % MEL;
        int i = ch / 3, j = ch % 3;
        int qb = 3 * i + (j - 1);
        float acc = bs[ch];
        #pragma unroll
        for (int c = 0; c < 3; ++c) {
            int q = qb + c;
            if (q >= 0 && q < MEL) {
                const float* wp = ws + ((j * 20 + i) * 3 + c) * 5;
                #pragma unroll
                for (int k = 0; k < 5; ++k) acc += xt[tt + k][q] * wp[k];
            }
        }
        out[(size_t)bb * SS * MEL + (size_t)(t0 + tt) * MEL + ch] =
            __float2half(acc + xt[tt + 2][ch]);
    }
}

// ---------------- input GEMM per timestep: 64 batches x 64 cols ----------------
struct GemmArgs {
    const __half* A[NL];        // [b][S][K]
    const unsigned int* W[NL];  // [768][96]
    const float* bs[NL];        // [768]
    __half* C[NL];              // [CH][768][64]
    int K[NL];
    int KT[NL];
    int t0[NL];
};

__global__ __launch_bounds__(256) void gemm_pre(GemmArgs ga) {
    int j = blockIdx.z;
    int K = ga.K[j], KT = ga.KT[j];
    int tl = blockIdx.x;
    int tg = ga.t0[j] + tl;
    const __half* A = ga.A[j];
    const unsigned int* Wp = ga.W[j];
    const float* bs = ga.bs[j];
    __half* Cb = ga.C[j] + (size_t)tl * G4P * BB;
    int n0 = blockIdx.y * 64;
    __shared__ unsigned int As[8][68];
    __shared__ unsigned int Ws[8][68];
    __shared__ __align__(16) unsigned short Ct[64][72];
    int tid = threadIdx.x;
    int tx = tid & 15, ty = tid >> 4;
    int kpl = tid & 7, mg = tid >> 3;
    float acc[4][4];
    #pragma unroll
    for (int i = 0; i < 4; ++i)
        #pragma unroll
        for (int jn = 0; jn < 4; ++jn) acc[i][jn] = 0.f;

    for (int kt = 0; kt < KT; ++kt) {
        int kp = (kt << 3) + kpl;
        bool kv = (2 * kp < K);
        #pragma unroll
        for (int r = 0; r < 2; ++r) {
            int b = mg + (r << 5);
            As[kpl][b] = kv ? *(const unsigned int*)(A + ((size_t)b * SS + tg) * K + 2 * kp) : 0u;
            Ws[kpl][b] = kv ? Wp[(size_t)(n0 + b) * NKP + kp] : 0u;
        }
        __syncthreads();
        #pragma unroll
        for (int k = 0; k < 8; ++k) {
            unsigned int av[4], bv[4];
            #pragma unroll
            for (int i = 0; i < 4; ++i) av[i] = As[k][ty + (i << 4)];
            #pragma unroll
            for (int jn = 0; jn < 4; ++jn) bv[jn] = Ws[k][(tx << 2) + jn];
            #pragma unroll
            for (int i = 0; i < 4; ++i)
                #pragma unroll
                for (int jn = 0; jn < 4; ++jn) acc[i][jn] = fdot2u(bv[jn], av[i], acc[i][jn]);
        }
        __syncthreads();
    }
    // bias + transpose to [col][b] in LDS
    #pragma unroll
    for (int i = 0; i < 4; ++i) {
        int b = ty + (i << 4);
        #pragma unroll
        for (int jn = 0; jn < 4; ++jn) {
            int cc = (tx << 2) + jn;
            float v = acc[i][jn] + bs[n0 + cc];
            Ct[cc][b] = __half_as_ushort(__float2half(v));
        }
    }
    __syncthreads();
    // coalesced write: pre[tl][n0+rr][0..63]  (512 uint4 stores = full 64x64 tile)
    for (int w2 = tid; w2 < 64 * 8; w2 += 256) {
        int rr = w2 >> 3, seg = w2 & 7;
        uint4 val = *(const uint4*)&Ct[rr][seg << 3];
        *(uint4*)(Cb + ((size_t)(n0 + rr) * BB + (seg << 3))) = val;
    }
}

// ---------------- LSTM scan: 16 batches per WG, MFMA over real batch rows ----------------
struct ScanArgs {
    const __half* pre[NL];   // [CH][768][64]
    const uint4* wmf[NL];
    __half* hout[NL];
    float* hst[NL];
    float* cst[NL];
    int t0[NL];
};

__global__ __launch_bounds__(768) __attribute__((amdgpu_waves_per_eu(3, 3)))
void lstm_scan(ScanArgs sa) {
    int j = blockIdx.x >> 2, bg = blockIdx.x & 3;
    int tid = threadIdx.x;
    int wv = tid >> 6, lane = tid & 63;
    int r0 = lane >> 4, cl = lane & 15;
    int hid = (wv << 4) + cl;             // 0..191
    int t0 = sa.t0[j];
    const __half* preb = sa.pre[j];
    const uint4* wmfw = sa.wmf[j] + (size_t)wv * 4 * NKS * 64;
    __half* hout = sa.hout[j];
    float* hst = sa.hst[j];
    float* cst = sa.cst[j];
    int b0 = bg << 4;                     // batch base of WG
    int bl = r0 << 2;                     // local batch base of lane

    __shared__ __align__(16) unsigned short hsb[2][16][208];

    uint4 wfr[4][6];
    #pragma unroll
    for (int q = 0; q < 4; ++q)
        #pragma unroll
        for (int ks = 0; ks < NKS; ++ks)
            wfr[q][ks] = wmfw[(q * NKS + ks) * 64 + lane];
    #pragma unroll
    for (int q = 0; q < 4; ++q)
        #pragma unroll
        for (int ks = 0; ks < NKS; ++ks)
            asm volatile("" : "+v"(wfr[q][ks].x), "+v"(wfr[q][ks].y),
                              "+v"(wfr[q][ks].z), "+v"(wfr[q][ks].w));

    float c[4] = {0.f, 0.f, 0.f, 0.f};
    if (t0 > 0) {
        if (hid < HH) {
            #pragma unroll
            for (int r = 0; r < 4; ++r)
                c[r] = cst[(size_t)(b0 + bl + r) * HH + hid];
        }
        for (int idx = tid; idx < 16 * 208; idx += 768) {
            int b = idx / 208, k = idx % 208;
            float hv = (k < HH) ? hst[(size_t)(b0 + b) * HH + k] : 0.f;
            hsb[0][b][k] = __half_as_ushort(__float2half(hv));
        }
    } else {
        for (int idx = tid; idx < 16 * 208; idx += 768)
            hsb[0][idx / 208][idx % 208] = 0;
    }
    __syncthreads();

    const __half* pl[4];
    #pragma unroll
    for (int q = 0; q < 4; ++q)
        pl[q] = preb + ((size_t)(q * GP + hid) * BB + b0 + bl);

    uint2 pc[4];
    #pragma unroll
    for (int q = 0; q < 4; ++q) pc[q] = *(const uint2*)pl[q];

    float hl[4] = {0.f, 0.f, 0.f, 0.f};
    for (int t = 0; t < CH; ++t) {
        uint2 pn[4] = {{0u,0u},{0u,0u},{0u,0u},{0u,0u}};
        if (t + 1 < CH) {
            #pragma unroll
            for (int q = 0; q < 4; ++q)
                pn[q] = *(const uint2*)(pl[q] + (size_t)(t + 1) * G4P * BB);
        }
        const unsigned short* hrow = hsb[t & 1][cl];
        f32x4 a0 = {0.f,0.f,0.f,0.f}, a1 = a0, a2 = a0, a3 = a0;
        #pragma unroll
        for (int ks = 0; ks < NKS; ++ks) {
            WU hf;
            hf.u = *(const uint4*)(hrow + (ks << 5) + (r0 << 3));
            WU w0, w1, w2, w3;
            w0.u = wfr[0][ks]; w1.u = wfr[1][ks]; w2.u = wfr[2][ks]; w3.u = wfr[3][ks];
            a0 = __builtin_amdgcn_mfma_f32_16x16x32_f16(hf.f, w0.f, a0, 0, 0, 0);
            a1 = __builtin_amdgcn_mfma_f32_16x16x32_f16(hf.f, w1.f, a1, 0, 0, 0);
            a2 = __builtin_amdgcn_mfma_f32_16x16x32_f16(hf.f, w2.f, a2, 0, 0, 0);
            a3 = __builtin_amdgcn_mfma_f32_16x16x32_f16(hf.f, w3.f, a3, 0, 0, 0);
        }
        // in-register nonlinearity: lane owns (batch b0+bl+r, hidden hid)
        unsigned short* hnx = &hsb[(t + 1) & 1][0][0];
        #pragma unroll
        for (int r = 0; r < 4; ++r) {
            float gi = a0[r] + f16get(pc[0], r);
            float gf = a1[r] + f16get(pc[1], r);
            float gg = a2[r] + f16get(pc[2], r);
            float go = a3[r] + f16get(pc[3], r);
            float si = 1.f / (1.f + __expf(-gi));
            float sf = 1.f / (1.f + __expf(-gf));
            float so = 1.f / (1.f + __expf(-go));
            float tg = 1.f - 2.f / (__expf(2.f * gg) + 1.f);
            c[r] = sf * c[r] + si * tg;
            float hn = so * (1.f - 2.f / (__expf(2.f * c[r]) + 1.f));
            hl[r] = hn;
            __half hh = __float2half(hn);
            hnx[(bl + r) * 208 + hid] = __half_as_ushort(hh);
            if (hid < HH)
                hout[((size_t)(b0 + bl + r) * SS + t0 + t) * HH + hid] = hh;
        }
        __syncthreads();
        #pragma unroll
        for (int q = 0; q < 4; ++q) pc[q] = pn[q];
    }
    if (hid < HH) {
        #pragma unroll
        for (int r = 0; r < 4; ++r) {
            cst[(size_t)(b0 + bl + r) * HH + hid] = c[r];
            hst[(size_t)(b0 + bl + r) * HH + hid] = hl[r];
        }
    }
}

// ---------------- epilogue ----------------
__global__ void gather_last(const __half* __restrict__ hfin, const int* __restrict__ lens,
                            float* __restrict__ last) {
    int idx = blockIdx.x * blockDim.x + threadIdx.x;
    if (idx >= BB * HH) return;
    int b = idx / HH, d = idx % HH;
    int t = lens[b] - 1;
    t = t < 0 ? 0 : (t > SS - 1 ? SS - 1 : t);
    last[idx] = __half2float(hfin[((size_t)b * SS + t) * HH + d]);
}

__global__ __launch_bounds__(256) void post_gemm(const float* __restrict__ A,
                                                 const float* __restrict__ Bw,
                                                 const float* __restrict__ pb,
                                                 float* __restrict__ Cb) {
    __shared__ float As[16][68];
    __shared__ float Bs[16][68];
    int n0 = blockIdx.x * 64;
    int tid = threadIdx.x;
    int kk = tid & 15, q = tid >> 4;
    int tx = tid & 15, ty = tid >> 4;
    float acc[4][4];
    #pragma unroll
    for (int i = 0; i < 4; ++i)
        #pragma unroll
        for (int jj = 0; jj < 4; ++jj) acc[i][jj] = 0.f;
    for (int kt = 0; kt < 12; ++kt) {
        int kidx = kt * 16 + kk;
        bool kval = kidx < HH;
        #pragma unroll
        for (int r = 0; r < 4; ++r)
            As[kk][q + (r << 4)] = kval ? A[(size_t)(q + (r << 4)) * HH + kidx] : 0.f;
        #pragma unroll
        for (int r = 0; r < 4; ++r)
            Bs[kk][q + (r << 4)] = kval ? Bw[(size_t)(n0 + q + (r << 4)) * HH + kidx] : 0.f;
        __syncthreads();
        #pragma unroll
        for (int k = 0; k < 16; ++k) {
            float a[4], bv[4];
            #pragma unroll
            for (int i = 0; i < 4; ++i) a[i] = As[k][ty + (i << 4)];
            #pragma unroll
            for (int jj = 0; jj < 4; ++jj) bv[jj] = Bs[k][(tx << 2) + jj];
            #pragma unroll
            for (int i = 0; i < 4; ++i)
                #pragma unroll
                for (int jj = 0; jj < 4; ++jj) acc[i][jj] = fmaf(a[i], bv[jj], acc[i][jj]);
        }
        __syncthreads();
    }
    #pragma unroll
    for (int i = 0; i < 4; ++i) {
        int m = ty + (i << 4);
        #pragma unroll
        for (int jj = 0; jj < 4; ++jj) {
            int g = n0 + (tx << 2) + jj;
            float v = acc[i][jj] + pb[g];
            Cb[(size_t)m * NPOST + g] = v > 0.f ? v : 0.01f * v;
        }
    }
}

__global__ __launch_bounds__(256) void up_gemm(const float* __restrict__ A,
                                               const float* __restrict__ Bw,
                                               float* __restrict__ part) {
    __shared__ float As[16][68];
    __shared__ float Bs[16][68];
    int n0 = blockIdx.x * 64;
    int k0 = blockIdx.y * (NPOST / KSPL);
    float* Pb = part + (size_t)blockIdx.y * BB * NOUTP;
    int tid = threadIdx.x;
    int kk = tid & 15, q = tid >> 4;
    int tx = tid & 15, ty = tid >> 4;
    float acc[4][4];
    #pragma unroll
    for (int i = 0; i < 4; ++i)
        #pragma unroll
        for (int jj = 0; jj < 4; ++jj) acc[i][jj] = 0.f;
    for (int kt = 0; kt < (NPOST / KSPL) / 16; ++kt) {
        int kidx = k0 + kt * 16 + kk;
        #pragma unroll
        for (int r = 0; r < 4; ++r)
            As[kk][q + (r << 4)] = A[(size_t)(q + (r << 4)) * NPOST + kidx];
        #pragma unroll
        for (int r = 0; r < 4; ++r) {
            int g = n0 + q + (r << 4);
            Bs[kk][q + (r << 4)] = (g < NOUT) ? Bw[(size_t)g * NPOST + kidx] : 0.f;
        }
        __syncthreads();
        #pragma unroll
        for (int k = 0; k < 16; ++k) {
            float a[4], bv[4];
            #pragma unroll
            for (int i = 0; i < 4; ++i) a[i] = As[k][ty + (i << 4)];
            #pragma unroll
            for (int jj = 0; jj < 4; ++jj) bv[jj] = Bs[k][(tx << 2) + jj];
            #pragma unroll
            for (int i = 0; i < 4; ++i)
                #pragma unroll
                for (int jj = 0; jj < 4; ++jj) acc[i][jj] = fmaf(a[i], bv[jj], acc[i][jj]);
        }
        __syncthreads();
    }
    #pragma unroll
    for (int i = 0; i < 4; ++i) {
        int m = ty + (i << 4);
        #pragma unroll
        for (int jj = 0; jj < 4; ++jj) {
            int g = n0 + (tx << 2) + jj;
            Pb[(size_t)m * NOUTP + g] = acc[i][jj];
        }
    }
}

__global__ void up_reduce(const float* __restrict__ part, const float* __restrict__ ub,
                          float* __restrict__ out) {
    int idx = blockIdx.x * blockDim.x + threadIdx.x;
    if (idx >= BB * NOUT) return;
    int b = idx / NOUT, o = idx % NOUT;
    float acc = ub[o];
    #pragma unroll
    for (int ks = 0; ks < KSPL; ++ks)
        acc += part[((size_t)ks * BB + b) * NOUTP + o];
    out[(size_t)b * NOUT + o] = acc;
}

extern "C" void kernel_launch(void* const* d_in, const int* in_sizes, int n_in,
                              void* d_out, int out_size, void* d_ws, size_t ws_size,
                              hipStream_t stream) {
    const float* x        = (const float*)d_in[0];
    const int*   lens     = (const int*)d_in[1];
    const float* conv_w   = (const float*)d_in[2];
    const float* conv_b   = (const float*)d_in[3];
    const float* wih0     = (const float*)d_in[4];
    const float* wih_rest = (const float*)d_in[5];
    const float* whh      = (const float*)d_in[6];
    const float* bih      = (const float*)d_in[7];
    const float* bhh      = (const float*)d_in[8];
    const float* post_w   = (const float*)d_in[9];
    const float* post_b   = (const float*)d_in[10];
    const float* up_w     = (const float*)d_in[11];
    const float* up_b     = (const float*)d_in[12];
    float* out = (float*)d_out;
    (void)in_sizes; (void)n_in; (void)out_size;

    auto pad = [](size_t v) { return (v + 255) & ~(size_t)255; };
    const size_t szMel   = (size_t)BB * SS * MEL * 2;        // 7.9 MB
    const size_t szH     = (size_t)BB * SS * HH * 2;         // 23.6 MB
    const size_t szSlot  = (size_t)CH * G4P * BB * 2;        // 6.3 MB  [t][col][b] f16
    const size_t szWmf   = (size_t)NL * 12 * 4 * NKS * 64 * 16;
    const size_t szWihP  = (size_t)NL * G4P * NKP * 4;
    const size_t szBsP   = (size_t)NL * G4P * 4;
    const size_t szState = (size_t)BB * HH * 4;              // per layer
    const size_t szLast  = (size_t)BB * HH * 4;
    const size_t szPost  = (size_t)BB * NPOST * 4;
    const size_t szPart  = (size_t)KSPL * BB * NOUTP * 4;

    size_t commonSmall = pad(szWmf) + pad(szWihP) + pad(szBsP) + 2 * NL * pad(szState) +
                         pad(szLast) + pad(szPost) + pad(szPart) + 4096;
    size_t needWF = pad(szMel) + 4 * pad(szH) + 4 * pad(szSlot) + commonSmall;
    int wavefront = (ws_size >= needWF) ? 1 : 0;

    char* wsp = (char*)d_ws;
    size_t off = 0;
    auto alloc = [&](size_t bytes) -> void* {
        void* p = wsp + off;
        off = (off + bytes + 255) & ~(size_t)255;
        return p;
    };

    __half* melF = (__half*)alloc(szMel);
    __half* hbuf[NL];
    if (wavefront) {
        for (int l = 0; l < NL; ++l) hbuf[l] = (__half*)alloc(szH);
    } else {
        __half* p0 = (__half*)alloc(szH);
        __half* p1 = (__half*)alloc(szH);
        hbuf[0] = p0; hbuf[1] = p1; hbuf[2] = p0; hbuf[3] = p1;
    }
    __half* slot[NL];
    if (wavefront) {
        for (int l = 0; l < NL; ++l) slot[l] = (__half*)alloc(szSlot);
    } else {
        slot[0] = (__half*)alloc(szSlot);
        for (int l = 1; l < NL; ++l) slot[l] = slot[0];
    }
    uint4* wmf = (uint4*)alloc(szWmf);
    unsigned int* wihP = (unsigned int*)alloc(szWihP);
    float* bsP = (float*)alloc(szBsP);
    float* hstates = (float*)alloc(NL * pad(szState));
    float* cstates = (float*)alloc(NL * pad(szState));
    float* lastb = (float*)alloc(szLast);
    float* postb = (float*)alloc(szPost);
    float* partb = (float*)alloc(szPart);
    size_t stStride = pad(szState) / 4;

    prep_wmf<<<(NL * 12 * 4 * NKS * 64 + 255) / 256, 256, 0, stream>>>(whh, wmf);
    prep_wihP<<<(NL * G4P * NKP + 255) / 256, 256, 0, stream>>>(wih0, wih_rest, wihP);
    prep_bsumP<<<(NL * G4P + 255) / 256, 256, 0, stream>>>(bih, bhh, bsP);

    {
        __half* m0 = hbuf[0];
        __half* m1 = (__half*)((char*)hbuf[0] + pad(szMel));
        mel_block<float><<<dim3(BB, SS / TT), 256, 0, stream>>>(x, m0, conv_w + 0 * 900, conv_b + 0 * 60);
        mel_block<__half><<<dim3(BB, SS / TT), 256, 0, stream>>>(m0, m1, conv_w + 1 * 900, conv_b + 1 * 60);
        mel_block<__half><<<dim3(BB, SS / TT), 256, 0, stream>>>(m1, melF, conv_w + 2 * 900, conv_b + 2 * 60);
    }

    auto setGemmJob = [&](GemmArgs& ga, int nj, int l, int c) {
        ga.A[nj]  = (l == 0) ? melF : hbuf[l - 1];
        ga.K[nj]  = (l == 0) ? MEL : HH;
        ga.KT[nj] = (l == 0) ? 4 : 12;
        ga.W[nj]  = wihP + (size_t)l * G4P * NKP;
        ga.bs[nj] = bsP + (size_t)l * G4P;
        ga.C[nj]  = slot[l];
        ga.t0[nj] = c * CH;
    };
    auto setScanJob = [&](ScanArgs& sa, int nj, int l, int c) {
        sa.pre[nj]  = slot[l];
        sa.wmf[nj]  = wmf + (size_t)l * 12 * 4 * NKS * 64;
        sa.hout[nj] = hbuf[l];
        sa.hst[nj]  = hstates + (size_t)l * stStride;
        sa.cst[nj]  = cstates + (size_t)l * stStride;
        sa.t0[nj]   = c * CH;
    };

    if (wavefront) {
        for (int w = 0; w < NCH + NL - 1; ++w) {
            GemmArgs ga{};
            int njg = 0;
            for (int l = 0; l < NL; ++l) {
                int c = w - l;
                if (c < 0 || c >= NCH) continue;
                setGemmJob(ga, njg++, l, c);
            }
            if (njg) gemm_pre<<<dim3(CH, 12, njg), 256, 0, stream>>>(ga);
            ScanArgs sa{};
            int njs = 0;
            for (int l = 0; l < NL; ++l) {
                int c = w - l;
                if (c < 0 || c >= NCH) continue;
                setScanJob(sa, njs++, l, c);
            }
            if (njs) lstm_scan<<<dim3(njs * 4), 768, 0, stream>>>(sa);
        }
    } else {
        for (int l = 0; l < NL; ++l) {
            for (int c = 0; c < NCH; ++c) {
                GemmArgs ga{}; ScanArgs sa{};
                setGemmJob(ga, 0, l, c);
                gemm_pre<<<dim3(CH, 12, 1), 256, 0, stream>>>(ga);
                setScanJob(sa, 0, l, c);
                lstm_scan<<<dim3(4), 768, 0, stream>>>(sa);
            }
        }
    }

    gather_last<<<(BB * HH + 255) / 256, 256, 0, stream>>>(hbuf[NL - 1], lens, lastb);
    post_gemm<<<NPOST / 64, 256, 0, stream>>>(lastb, post_w, post_b, postb);
    up_gemm<<<dim3(NOUTP / 64, KSPL), 256, 0, stream>>>(postb, up_w, partb);
    up_reduce<<<(BB * NOUT + 255) / 256, 256, 0, stream>>>(partb, up_b, out);
}